// Round 4
// baseline (390.403 us; speedup 1.0000x reference)
//
#include <hip/hip_runtime.h>
#include <math.h>

// Problem constants (fixed by setup_inputs)
#define NODES_TOT 7424      // 64 * 116
#define EDGES     237568    // NODES_TOT * 32
#define BATCH     64
#define NN        116
#define KDIM      7424      // FC K dim
#define N1        7424      // FC1 out
#define N2        13456     // FC2 out (116*116)
#define NKB       116       // KDIM / 64 k-steps total
#define KSPLIT1   16
#define KSPLIT2   8

typedef __attribute__((ext_vector_type(8))) short bf16x8;
typedef __attribute__((ext_vector_type(4))) float f32x4;
typedef __attribute__((ext_vector_type(4))) short s16x4;

__device__ __forceinline__ float mish_f(float v) {
    float sp = fmaxf(v, 0.0f) + log1pf(expf(-fabsf(v)));
    return v * tanhf(sp);
}

__device__ __forceinline__ unsigned short bf_rne(float f) {
    unsigned u = __float_as_uint(f);
    u += 0x7fffu + ((u >> 16) & 1u);
    return (unsigned short)(u >> 16);
}

// ---------- small utility ----------
__global__ void zero_kernel(int* __restrict__ p, int n) {
    int i = blockIdx.x * 256 + threadIdx.x;
    if (i < n) p[i] = 0;
}

// ---------- CSR build ----------
__global__ void hist_kernel(const int* __restrict__ dst, int* __restrict__ hist) {
    int e = blockIdx.x * 256 + threadIdx.x;
    if (e < EDGES) atomicAdd(&hist[dst[e]], 1);
}

__global__ void scan_kernel(const int* __restrict__ hist, int* __restrict__ row_start,
                            int* __restrict__ cursor) {
    __shared__ int s[1024];
    int t = threadIdx.x;
    int base = t * 8;
    int loc[8];
    int sum = 0;
    #pragma unroll
    for (int c = 0; c < 8; ++c) {
        int idx = base + c;
        int v = (idx < NODES_TOT) ? hist[idx] : 0;
        loc[c] = sum;
        sum += v;
    }
    s[t] = sum;
    __syncthreads();
    for (int off = 1; off < 1024; off <<= 1) {
        int v = (t >= off) ? s[t - off] : 0;
        __syncthreads();
        s[t] += v;
        __syncthreads();
    }
    int excl = s[t] - sum;
    #pragma unroll
    for (int c = 0; c < 8; ++c) {
        int idx = base + c;
        if (idx < NODES_TOT) {
            int r = excl + loc[c];
            row_start[idx] = r;
            cursor[idx] = r;
        }
    }
}

__global__ void csr_fill_kernel(const int* __restrict__ src, const int* __restrict__ dst,
                                int* __restrict__ cursor, int* __restrict__ csr_src) {
    int e = blockIdx.x * 256 + threadIdx.x;
    if (e < EDGES) {
        int p = atomicAdd(&cursor[dst[e]], 1);
        csr_src[p] = src[e];
    }
}

// ---------- fused mean-aggregate + SAGE linear + mish ----------
template <bool BF>
__global__ void __launch_bounds__(256) conv_kernel(
        const float* __restrict__ x, const int* __restrict__ csr_src,
        const int* __restrict__ row_start, const int* __restrict__ deg_arr,
        const float* __restrict__ w_l, const float* __restrict__ b_l,
        const float* __restrict__ w_r, void* __restrict__ h_out_v) {
    __shared__ float wlT[64 * 64];   // [k][f]
    __shared__ float wrT[64 * 64];   // [k][f]
    __shared__ float mv[4][64];
    __shared__ float xv[4][64];
    int t = threadIdx.x;
    for (int i = 0; i < 16; ++i) {
        int idx = t + i * 256;
        int f = idx >> 6, k = idx & 63;
        wlT[k * 64 + f] = w_l[idx];
        wrT[k * 64 + f] = w_r[idx];
    }
    int g = t >> 6, f = t & 63;
    __syncthreads();
    for (int nb = blockIdx.x * 4; nb < NODES_TOT; nb += gridDim.x * 4) {
        int node = nb + g;
        int deg = deg_arr[node];
        int rs = row_start[node];
        float sum = 0.f;
        for (int e = 0; e < deg; ++e) {
            int s = csr_src[rs + e];
            sum += x[s * 64 + f];
        }
        float mean = sum / (float)max(deg, 1);
        mv[g][f] = mean;
        xv[g][f] = x[node * 64 + f];
        __syncthreads();
        float o = b_l[f];
        #pragma unroll
        for (int k = 0; k < 64; ++k) {
            o = fmaf(mv[g][k], wlT[k * 64 + f], o);
            o = fmaf(xv[g][k], wrT[k * 64 + f], o);
        }
        float m = mish_f(o);
        if (BF) ((unsigned short*)h_out_v)[node * 64 + f] = bf_rne(m);
        else    ((float*)h_out_v)[node * 64 + f] = m;
        __syncthreads();
    }
}

// ---------- bf16-MFMA tiled GEMM: Cp[by][64][N] = A[64][Kslice] * W[Ntile][Kslice]^T ----------
// W staged via LDS (fp32->bf16 in-register), instruction-coalesced global loads:
// thread (row=t>>2, q=t&3) loads f32x4 at float offs q*4 + i*16 -> lanes 0-3
// cover one contiguous 64B line per instruction. A is read directly from global
// (fragment load A[g*16+l15][k0+fw*8] is line-coalesced: 4 lanes x 16B = 64B line).
template <int KSHIFT>
__global__ void __launch_bounds__(256) gemm_tile(
        const unsigned short* __restrict__ Abf, const float* __restrict__ W,
        float* __restrict__ Cp, int N) {
    __shared__ __align__(16) short Wsh[512 * 8];   // 8 KB: chunk (f*64 + r) of 8 bf16
    int t = threadIdx.x;
    int bx = blockIdx.x, by = blockIdx.y;
    int kb0 = (by * NKB) >> KSHIFT;
    int kb1 = ((by + 1) * NKB) >> KSHIFT;
    int n0 = bx * 64;
    // staging indices
    int r = t >> 2, q = t & 3;
    int wr = n0 + r; if (wr >= N) wr = N - 1;
    const float* wsrc = W + (size_t)wr * KDIM + q * 4;
    int half = q & 1;            // which 4-short half of the 8-bf16 chunk
    int fbase = q >> 1;          // k-octet base (i*2 + fbase)
    // compute indices
    int wv = t >> 6, l = t & 63, l15 = l & 15, hi = l >> 4;
    f32x4 acc[4];
    #pragma unroll
    for (int g = 0; g < 4; ++g) acc[g] = (f32x4){0.f, 0.f, 0.f, 0.f};

    // prologue: load first k-step of W
    f32x4 w[4];
    {
        size_t k0 = (size_t)kb0 * 64;
        #pragma unroll
        for (int i = 0; i < 4; ++i) w[i] = *(const f32x4*)(wsrc + k0 + i * 16);
    }
    for (int kb = kb0; kb < kb1; ++kb) {
        // convert 16 fp32 -> 16 bf16
        s16x4 cv[4];
        #pragma unroll
        for (int i = 0; i < 4; ++i)
            #pragma unroll
            for (int j = 0; j < 4; ++j) cv[i][j] = (short)bf_rne(w[i][j]);
        __syncthreads();   // previous iter's LDS reads complete
        #pragma unroll
        for (int i = 0; i < 4; ++i)
            *(s16x4*)&Wsh[((i * 2 + fbase) * 64 + r) * 8 + half * 4] = cv[i];
        __syncthreads();
        // prefetch next k-step while MFMA phase runs
        if (kb + 1 < kb1) {
            size_t kn = (size_t)(kb + 1) * 64;
            #pragma unroll
            for (int i = 0; i < 4; ++i) w[i] = *(const f32x4*)(wsrc + kn + i * 16);
        }
        size_t k0 = (size_t)kb * 64;
        #pragma unroll
        for (int s = 0; s < 2; ++s) {
            int fw = s * 4 + hi;
            bf16x8 bh = *(const bf16x8*)&Wsh[(fw * 64 + wv * 16 + l15) * 8];
            #pragma unroll
            for (int g = 0; g < 4; ++g) {
                bf16x8 av = *(const bf16x8*)(Abf + (size_t)(g * 16 + l15) * KDIM + k0 + fw * 8);
                acc[g] = __builtin_amdgcn_mfma_f32_16x16x32_bf16(av, bh, acc[g], 0, 0, 0);
            }
        }
    }
    // store partials
    int gn = n0 + wv * 16 + l15;
    if (gn < N) {
        float* cp = Cp + (size_t)by * 64 * N;
        #pragma unroll
        for (int g = 0; g < 4; ++g)
            #pragma unroll
            for (int rr = 0; rr < 4; ++rr)
                cp[(size_t)(g * 16 + hi * 4 + rr) * N + gn] = acc[g][rr];
    }
}

// ---------- reduce partials + bias + mish + bf16 cast (FC1 epilogue) ----------
__global__ void reduce1_kernel(const float* __restrict__ Cp, const float* __restrict__ b,
                               unsigned short* __restrict__ A2) {
    int i4 = (blockIdx.x * 256 + threadIdx.x) * 4;
    if (i4 >= BATCH * N1) return;
    int n = i4 % N1;
    f32x4 acc = *(const f32x4*)(b + n);
    #pragma unroll
    for (int s = 0; s < KSPLIT1; ++s)
        acc += *(const f32x4*)(Cp + (size_t)s * BATCH * N1 + i4);
    s16x4 o;
    #pragma unroll
    for (int j = 0; j < 4; ++j) o[j] = (short)bf_rne(mish_f(acc[j]));
    *(s16x4*)(A2 + i4) = o;
}

// ---------- reduce partials + bias (FC2 epilogue) ----------
__global__ void reduce2_kernel(const float* __restrict__ Cp, const float* __restrict__ b,
                               float* __restrict__ C2) {
    int i4 = (blockIdx.x * 256 + threadIdx.x) * 4;
    if (i4 >= BATCH * N2) return;
    int n = i4 % N2;
    f32x4 acc = *(const f32x4*)(b + n);
    #pragma unroll
    for (int s = 0; s < KSPLIT2; ++s)
        acc += *(const f32x4*)(Cp + (size_t)s * BATCH * N2 + i4);
    *(f32x4*)(C2 + i4) = acc;
}

// ---------- symmetrize + unit diagonal (C2 L2-resident, bias pre-added) ----------
__global__ void sym_kernel(const float* __restrict__ C2, float* __restrict__ out) {
    int tid = blockIdx.x * 256 + threadIdx.x;
    if (tid >= BATCH * NN * NN) return;
    int j = tid % NN;
    int r = tid / NN;
    int i = r % NN;
    int b = r / NN;
    float v;
    if (i == j) {
        v = 1.0f;
    } else {
        v = 0.5f * (C2[(size_t)b * N2 + i * NN + j] + C2[(size_t)b * N2 + j * NN + i]);
    }
    out[tid] = v;
}

extern "C" void kernel_launch(void* const* d_in, const int* in_sizes, int n_in,
                              void* d_out, int out_size, void* d_ws, size_t ws_size,
                              hipStream_t stream) {
    const float* z     = (const float*)d_in[0];
    const int*   edge  = (const int*)d_in[1];
    const float* w1_l  = (const float*)d_in[3];
    const float* b1_l  = (const float*)d_in[4];
    const float* w1_r  = (const float*)d_in[5];
    const float* w2_l  = (const float*)d_in[6];
    const float* b2_l  = (const float*)d_in[7];
    const float* w2_r  = (const float*)d_in[8];
    const float* fc1_w = (const float*)d_in[9];
    const float* fc1_b = (const float*)d_in[10];
    const float* fc2_w = (const float*)d_in[11];
    const float* fc2_b = (const float*)d_in[12];
    float* out = (float*)d_out;

    char* ws = (char*)d_ws;
    size_t off = 0;
    auto alloc = [&](size_t bytes) {
        void* p = ws + off;
        off = (off + bytes + 255) & ~(size_t)255;
        return p;
    };
    int*            hist      = (int*)alloc(NODES_TOT * 4);
    int*            row_start = (int*)alloc(NODES_TOT * 4);
    int*            cursor    = (int*)alloc(NODES_TOT * 4);
    int*            csr_src   = (int*)alloc((size_t)EDGES * 4);
    float*          h1        = (float*)alloc((size_t)NODES_TOT * 64 * 4);
    unsigned short* A1        = (unsigned short*)alloc((size_t)NODES_TOT * 64 * 2);
    float*          Cp1       = (float*)alloc((size_t)KSPLIT1 * BATCH * N1 * 4);
    unsigned short* A2        = (unsigned short*)alloc((size_t)BATCH * N1 * 2);
    float*          Cp2       = (float*)alloc((size_t)KSPLIT2 * BATCH * N2 * 4);
    float*          C2        = (float*)alloc((size_t)BATCH * N2 * 4);

    const int* src = edge;
    const int* dst = edge + EDGES;

    zero_kernel<<<(NODES_TOT + 255) / 256, 256, 0, stream>>>(hist, NODES_TOT);
    hist_kernel<<<(EDGES + 255) / 256, 256, 0, stream>>>(dst, hist);
    scan_kernel<<<1, 1024, 0, stream>>>(hist, row_start, cursor);
    csr_fill_kernel<<<(EDGES + 255) / 256, 256, 0, stream>>>(src, dst, cursor, csr_src);

    conv_kernel<false><<<928, 256, 0, stream>>>(z, csr_src, row_start, hist, w1_l, b1_l, w1_r, h1);
    conv_kernel<true><<<928, 256, 0, stream>>>(h1, csr_src, row_start, hist, w2_l, b2_l, w2_r, A1);

    // FC1: partials over 16 k-splits, then fused reduce+bias+mish+cast
    gemm_tile<4><<<dim3(N1 / 64, KSPLIT1), 256, 0, stream>>>(A1, fc1_w, Cp1, N1);
    reduce1_kernel<<<(BATCH * N1 / 4 + 255) / 256, 256, 0, stream>>>(Cp1, fc1_b, A2);

    // FC2: partials over 8 k-splits
    gemm_tile<3><<<dim3((N2 + 63) / 64, KSPLIT2), 256, 0, stream>>>(A2, fc2_w, Cp2, N2);
    reduce2_kernel<<<(BATCH * N2 / 4 + 255) / 256, 256, 0, stream>>>(Cp2, fc2_b, C2);

    sym_kernel<<<(BATCH * NN * NN + 255) / 256, 256, 0, stream>>>(C2, out);
}

// Round 5
// 324.408 us; speedup vs baseline: 1.2034x; 1.2034x over previous
//
#include <hip/hip_runtime.h>
#include <math.h>

// Problem constants (fixed by setup_inputs)
#define NODES_TOT 7424      // 64 * 116
#define EDGES     237568    // NODES_TOT * 32
#define BATCH     64
#define NN        116
#define KDIM      7424      // FC K dim
#define N1        7424      // FC1 out
#define N2        13456     // FC2 out (116*116)
#define NKB       116       // KDIM / 64 k-steps total
#define KSPLIT    8

typedef __attribute__((ext_vector_type(8))) short bf16x8;
typedef __attribute__((ext_vector_type(4))) float f32x4;
typedef __attribute__((ext_vector_type(4))) short s16x4;

__device__ __forceinline__ float mish_f(float v) {
    float sp = fmaxf(v, 0.0f) + log1pf(expf(-fabsf(v)));
    return v * tanhf(sp);
}

__device__ __forceinline__ unsigned short bf_rne(float f) {
    unsigned u = __float_as_uint(f);
    u += 0x7fffu + ((u >> 16) & 1u);
    return (unsigned short)(u >> 16);
}

// ---------- small utility ----------
__global__ void zero_kernel(int* __restrict__ p, int n) {
    int i = blockIdx.x * 256 + threadIdx.x;
    if (i < n) p[i] = 0;
}

// ---------- CSR build ----------
__global__ void hist_kernel(const int* __restrict__ dst, int* __restrict__ hist) {
    int e = blockIdx.x * 256 + threadIdx.x;
    if (e < EDGES) atomicAdd(&hist[dst[e]], 1);
}

__global__ void scan_kernel(const int* __restrict__ hist, int* __restrict__ row_start,
                            int* __restrict__ cursor) {
    __shared__ int s[1024];
    int t = threadIdx.x;
    int base = t * 8;
    int loc[8];
    int sum = 0;
    #pragma unroll
    for (int c = 0; c < 8; ++c) {
        int idx = base + c;
        int v = (idx < NODES_TOT) ? hist[idx] : 0;
        loc[c] = sum;
        sum += v;
    }
    s[t] = sum;
    __syncthreads();
    for (int off = 1; off < 1024; off <<= 1) {
        int v = (t >= off) ? s[t - off] : 0;
        __syncthreads();
        s[t] += v;
        __syncthreads();
    }
    int excl = s[t] - sum;
    #pragma unroll
    for (int c = 0; c < 8; ++c) {
        int idx = base + c;
        if (idx < NODES_TOT) {
            int r = excl + loc[c];
            row_start[idx] = r;
            cursor[idx] = r;
        }
    }
}

__global__ void csr_fill_kernel(const int* __restrict__ src, const int* __restrict__ dst,
                                int* __restrict__ cursor, int* __restrict__ csr_src) {
    int e = blockIdx.x * 256 + threadIdx.x;
    if (e < EDGES) {
        int p = atomicAdd(&cursor[dst[e]], 1);
        csr_src[p] = src[e];
    }
}

// ---------- fused mean-aggregate + SAGE linear + mish ----------
template <bool BF>
__global__ void __launch_bounds__(256) conv_kernel(
        const float* __restrict__ x, const int* __restrict__ csr_src,
        const int* __restrict__ row_start, const int* __restrict__ deg_arr,
        const float* __restrict__ w_l, const float* __restrict__ b_l,
        const float* __restrict__ w_r, void* __restrict__ h_out_v) {
    __shared__ float wlT[64 * 64];   // [k][f]
    __shared__ float wrT[64 * 64];   // [k][f]
    __shared__ float mv[4][64];
    __shared__ float xv[4][64];
    int t = threadIdx.x;
    for (int i = 0; i < 16; ++i) {
        int idx = t + i * 256;
        int f = idx >> 6, k = idx & 63;
        wlT[k * 64 + f] = w_l[idx];
        wrT[k * 64 + f] = w_r[idx];
    }
    int g = t >> 6, f = t & 63;
    __syncthreads();
    for (int nb = blockIdx.x * 4; nb < NODES_TOT; nb += gridDim.x * 4) {
        int node = nb + g;
        int deg = deg_arr[node];
        int rs = row_start[node];
        float sum = 0.f;
        for (int e = 0; e < deg; ++e) {
            int s = csr_src[rs + e];
            sum += x[s * 64 + f];
        }
        float mean = sum / (float)max(deg, 1);
        mv[g][f] = mean;
        xv[g][f] = x[node * 64 + f];
        __syncthreads();
        float o = b_l[f];
        #pragma unroll
        for (int k = 0; k < 64; ++k) {
            o = fmaf(mv[g][k], wlT[k * 64 + f], o);
            o = fmaf(xv[g][k], wrT[k * 64 + f], o);
        }
        float m = mish_f(o);
        if (BF) ((unsigned short*)h_out_v)[node * 64 + f] = bf_rne(m);
        else    ((float*)h_out_v)[node * 64 + f] = m;
        __syncthreads();
    }
}

// ---------- bf16-MFMA tiled GEMM, double-buffered LDS, 1 raw barrier / k-step ----------
// Cp[by][64][N] = A[64][Kslice] * W[Ntile][Kslice]^T
// LDS chunk layout: 16B chunk (f*64 + row), f = k-octet 0..7 within the 64-k step.
// W staged fp32->bf16 in-register; both A and W staging loads are line-coalesced
// (4 consecutive lanes cover one 64B line). Raw s_barrier (lgkmcnt(0) only, no
// vmcnt drain) lets next-next-step global loads stay in flight across barriers.
template <int KSHIFT>
__global__ void __launch_bounds__(256) gemm_tile(
        const unsigned short* __restrict__ Abf, const float* __restrict__ W,
        float* __restrict__ Cp, int N) {
    __shared__ __align__(16) short Wsh[2][4096];
    __shared__ __align__(16) short Ash[2][4096];
    int t = threadIdx.x;
    int bx = blockIdx.x, by = blockIdx.y;
    int kb0 = (by * NKB) >> KSHIFT;
    int kb1 = ((by + 1) * NKB) >> KSHIFT;
    int S = kb1 - kb0;                 // 14 or 15 k-steps
    int n0 = bx * 64;
    // staging indices: row r = t>>2, quad q = t&3 (4 lanes cover one 64B line)
    int r = t >> 2, q = t & 3;
    int wr = n0 + r; if (wr >= N) wr = N - 1;
    const float*          wsrc = W   + (size_t)wr * KDIM + (size_t)kb0 * 64 + q * 4;
    const unsigned short* asrc = Abf + (size_t)r  * KDIM + (size_t)kb0 * 64 + q * 8;
    int fb = q >> 1, hf = q & 1;       // W LDS placement: octet i*2+fb, half hf
    // compute indices
    int wv = t >> 6, l = t & 63, l15 = l & 15, hi = l >> 4;
    f32x4 acc[4];
    #pragma unroll
    for (int g = 0; g < 4; ++g) acc[g] = (f32x4){0.f, 0.f, 0.f, 0.f};

    f32x4 wA0, wA1, wA2, wA3, wB0, wB1, wB2, wB3;
    bf16x8 aA0, aA1, aB0, aB1;

#define ISSUE(W0, W1, W2, W3, A0, A1, step) do {                          \
        size_t kk = (size_t)(step) * 64;                                  \
        W0 = *(const f32x4*)(wsrc + kk);                                  \
        W1 = *(const f32x4*)(wsrc + kk + 16);                             \
        W2 = *(const f32x4*)(wsrc + kk + 32);                             \
        W3 = *(const f32x4*)(wsrc + kk + 48);                             \
        A0 = *(const bf16x8*)(asrc + kk);                                 \
        A1 = *(const bf16x8*)(asrc + kk + 32);                            \
    } while (0)

#define CONVWRITE(W0, W1, W2, W3, A0, A1, b) do {                         \
        s16x4 cv0, cv1, cv2, cv3;                                         \
        _Pragma("unroll")                                                 \
        for (int j = 0; j < 4; ++j) {                                     \
            cv0[j] = (short)bf_rne(W0[j]);                                \
            cv1[j] = (short)bf_rne(W1[j]);                                \
            cv2[j] = (short)bf_rne(W2[j]);                                \
            cv3[j] = (short)bf_rne(W3[j]);                                \
        }                                                                 \
        *(s16x4*)&Wsh[b][((0 * 2 + fb) * 64 + r) * 8 + hf * 4] = cv0;     \
        *(s16x4*)&Wsh[b][((1 * 2 + fb) * 64 + r) * 8 + hf * 4] = cv1;     \
        *(s16x4*)&Wsh[b][((2 * 2 + fb) * 64 + r) * 8 + hf * 4] = cv2;     \
        *(s16x4*)&Wsh[b][((3 * 2 + fb) * 64 + r) * 8 + hf * 4] = cv3;     \
        *(bf16x8*)&Ash[b][(q * 64 + r) * 8] = A0;                         \
        *(bf16x8*)&Ash[b][((q + 4) * 64 + r) * 8] = A1;                   \
    } while (0)

#define MFMAPH(b) do {                                                    \
        _Pragma("unroll")                                                 \
        for (int s = 0; s < 2; ++s) {                                     \
            int fw = s * 4 + hi;                                          \
            bf16x8 bh = *(const bf16x8*)&Wsh[b][(fw * 64 + wv * 16 + l15) * 8]; \
            _Pragma("unroll")                                             \
            for (int g = 0; g < 4; ++g) {                                 \
                bf16x8 av = *(const bf16x8*)&Ash[b][(fw * 64 + g * 16 + l15) * 8]; \
                acc[g] = __builtin_amdgcn_mfma_f32_16x16x32_bf16(av, bh, acc[g], 0, 0, 0); \
            }                                                             \
        }                                                                 \
    } while (0)

#define BAR() asm volatile("s_waitcnt lgkmcnt(0)\n\ts_barrier" ::: "memory")

    // prologue: S >= 2 always
    ISSUE(wA0, wA1, wA2, wA3, aA0, aA1, 0);
    ISSUE(wB0, wB1, wB2, wB3, aB0, aB1, 1);
    CONVWRITE(wA0, wA1, wA2, wA3, aA0, aA1, 0);
    BAR();

    int i = 0;
    for (; i + 1 < S - 1; i += 2) {
        if (i + 2 < S) ISSUE(wA0, wA1, wA2, wA3, aA0, aA1, i + 2);
        MFMAPH(0);                                       // step i
        CONVWRITE(wB0, wB1, wB2, wB3, aB0, aB1, 1);      // step i+1 -> LDS1
        BAR();
        if (i + 3 < S) ISSUE(wB0, wB1, wB2, wB3, aB0, aB1, i + 3);
        MFMAPH(1);                                       // step i+1
        CONVWRITE(wA0, wA1, wA2, wA3, aA0, aA1, 0);      // step i+2 -> LDS0
        BAR();
    }
    if (i < S - 1) {           // S even: one leftover body
        MFMAPH(0);                                       // step S-2
        CONVWRITE(wB0, wB1, wB2, wB3, aB0, aB1, 1);      // step S-1 -> LDS1
        BAR();
        MFMAPH(1);                                       // step S-1
    } else {                   // S odd
        MFMAPH(0);                                       // step S-1
    }

#undef ISSUE
#undef CONVWRITE
#undef MFMAPH
#undef BAR

    // store partials
    int gn = n0 + wv * 16 + l15;
    if (gn < N) {
        float* cp = Cp + (size_t)by * 64 * N;
        #pragma unroll
        for (int g = 0; g < 4; ++g)
            #pragma unroll
            for (int rr = 0; rr < 4; ++rr)
                cp[(size_t)(g * 16 + hi * 4 + rr) * N + gn] = acc[g][rr];
    }
}

// ---------- reduce partials + bias + mish + bf16 cast (FC1 epilogue) ----------
__global__ void reduce1_kernel(const float* __restrict__ Cp, const float* __restrict__ b,
                               unsigned short* __restrict__ A2) {
    int i4 = (blockIdx.x * 256 + threadIdx.x) * 4;
    if (i4 >= BATCH * N1) return;
    int n = i4 % N1;
    f32x4 acc = *(const f32x4*)(b + n);
    #pragma unroll
    for (int s = 0; s < KSPLIT; ++s)
        acc += *(const f32x4*)(Cp + (size_t)s * BATCH * N1 + i4);
    s16x4 o;
    #pragma unroll
    for (int j = 0; j < 4; ++j) o[j] = (short)bf_rne(mish_f(acc[j]));
    *(s16x4*)(A2 + i4) = o;
}

// ---------- reduce partials + bias (FC2 epilogue) ----------
__global__ void reduce2_kernel(const float* __restrict__ Cp, const float* __restrict__ b,
                               float* __restrict__ C2) {
    int i4 = (blockIdx.x * 256 + threadIdx.x) * 4;
    if (i4 >= BATCH * N2) return;
    int n = i4 % N2;
    f32x4 acc = *(const f32x4*)(b + n);
    #pragma unroll
    for (int s = 0; s < KSPLIT; ++s)
        acc += *(const f32x4*)(Cp + (size_t)s * BATCH * N2 + i4);
    *(f32x4*)(C2 + i4) = acc;
}

// ---------- symmetrize + unit diagonal (C2 L2-resident, bias pre-added) ----------
__global__ void sym_kernel(const float* __restrict__ C2, float* __restrict__ out) {
    int tid = blockIdx.x * 256 + threadIdx.x;
    if (tid >= BATCH * NN * NN) return;
    int j = tid % NN;
    int r = tid / NN;
    int i = r % NN;
    int b = r / NN;
    float v;
    if (i == j) {
        v = 1.0f;
    } else {
        v = 0.5f * (C2[(size_t)b * N2 + i * NN + j] + C2[(size_t)b * N2 + j * NN + i]);
    }
    out[tid] = v;
}

extern "C" void kernel_launch(void* const* d_in, const int* in_sizes, int n_in,
                              void* d_out, int out_size, void* d_ws, size_t ws_size,
                              hipStream_t stream) {
    const float* z     = (const float*)d_in[0];
    const int*   edge  = (const int*)d_in[1];
    const float* w1_l  = (const float*)d_in[3];
    const float* b1_l  = (const float*)d_in[4];
    const float* w1_r  = (const float*)d_in[5];
    const float* w2_l  = (const float*)d_in[6];
    const float* b2_l  = (const float*)d_in[7];
    const float* w2_r  = (const float*)d_in[8];
    const float* fc1_w = (const float*)d_in[9];
    const float* fc1_b = (const float*)d_in[10];
    const float* fc2_w = (const float*)d_in[11];
    const float* fc2_b = (const float*)d_in[12];
    float* out = (float*)d_out;

    char* ws = (char*)d_ws;
    size_t off = 0;
    auto alloc = [&](size_t bytes) {
        void* p = ws + off;
        off = (off + bytes + 255) & ~(size_t)255;
        return p;
    };
    int*            hist      = (int*)alloc(NODES_TOT * 4);
    int*            row_start = (int*)alloc(NODES_TOT * 4);
    int*            cursor    = (int*)alloc(NODES_TOT * 4);
    int*            csr_src   = (int*)alloc((size_t)EDGES * 4);
    float*          h1        = (float*)alloc((size_t)NODES_TOT * 64 * 4);
    unsigned short* A1        = (unsigned short*)alloc((size_t)NODES_TOT * 64 * 2);
    float*          Cp1       = (float*)alloc((size_t)KSPLIT * BATCH * N1 * 4);
    unsigned short* A2        = (unsigned short*)alloc((size_t)BATCH * N1 * 2);
    float*          Cp2       = (float*)alloc((size_t)KSPLIT * BATCH * N2 * 4);
    float*          C2        = (float*)alloc((size_t)BATCH * N2 * 4);

    const int* src = edge;
    const int* dst = edge + EDGES;

    zero_kernel<<<(NODES_TOT + 255) / 256, 256, 0, stream>>>(hist, NODES_TOT);
    hist_kernel<<<(EDGES + 255) / 256, 256, 0, stream>>>(dst, hist);
    scan_kernel<<<1, 1024, 0, stream>>>(hist, row_start, cursor);
    csr_fill_kernel<<<(EDGES + 255) / 256, 256, 0, stream>>>(src, dst, cursor, csr_src);

    conv_kernel<false><<<928, 256, 0, stream>>>(z, csr_src, row_start, hist, w1_l, b1_l, w1_r, h1);
    conv_kernel<true><<<928, 256, 0, stream>>>(h1, csr_src, row_start, hist, w2_l, b2_l, w2_r, A1);

    // FC1: partials over 8 k-splits, then fused reduce+bias+mish+cast
    gemm_tile<3><<<dim3(N1 / 64, KSPLIT), 256, 0, stream>>>(A1, fc1_w, Cp1, N1);
    reduce1_kernel<<<(BATCH * N1 / 4 + 255) / 256, 256, 0, stream>>>(Cp1, fc1_b, A2);

    // FC2: partials over 8 k-splits
    gemm_tile<3><<<dim3((N2 + 63) / 64, KSPLIT), 256, 0, stream>>>(A2, fc2_w, Cp2, N2);
    reduce2_kernel<<<(BATCH * N2 / 4 + 255) / 256, 256, 0, stream>>>(Cp2, fc2_b, C2);

    sym_kernel<<<(BATCH * NN * NN + 255) / 256, 256, 0, stream>>>(C2, out);
}